// Round 1
// baseline (518.555 us; speedup 1.0000x reference)
//
#include <hip/hip_runtime.h>
#include <hip/hip_bf16.h>

// RGCN 3-layer forward on MI355X — R5: phase-scheduled GEMM (T3+T4+T5).
//   256x256 tile, 8 waves (2M x 4N), BK=32, 4-deep LDS ring (128 KiB).
//   Per K-tile: 2 phases x {ds_read frags | stage 1 slab | barrier |
//   lgkmcnt(0) | setprio(1) 16xMFMA setprio(0) | counted vmcnt | barrier}.
//   vmcnt(8) steady state (slabs staged 3 K-tiles ahead), 4/0 tail drain.
//   N padded 1152->1280 (5 tiles); pad B rows uninit (never stored),
//   chunk swizzle slot = kc ^ ((row>>1)&3) for 64 B rows (conflict-free
//   at 8-lane ds_read_b128 granularity). Bijective m204 XCD swizzle.
//   Rest as R4: CSR preprocess, fused [root|W0|W1] B^T, wave-per-node agg.

#define D 384
#define NC 1152      // valid C columns (TC stride)
#define NP 1280      // padded B rows for BN=256 tiling
#define BM 256
#define BN 256
#define BK 32
#define NKT (D / BK)   // 12 K-tiles
#define NTN (NP / BN)  // 5 N-tiles

typedef __attribute__((ext_vector_type(8))) short short8;
typedef __attribute__((ext_vector_type(4))) float floatx4;
typedef unsigned int uint;
typedef unsigned short ushort;

#define BAR() asm volatile("s_barrier" ::: "memory")
#define WAIT_LGKM0() asm volatile("s_waitcnt lgkmcnt(0)" ::: "memory")
#define WAIT_VM8() asm volatile("s_waitcnt vmcnt(8)" ::: "memory")
#define WAIT_VM4() asm volatile("s_waitcnt vmcnt(4)" ::: "memory")
#define WAIT_VM0() asm volatile("s_waitcnt vmcnt(0)" ::: "memory")

__device__ __forceinline__ void load_lds16(const void* g, void* l) {
    __builtin_amdgcn_global_load_lds(
        (const __attribute__((address_space(1))) void*)g,
        (__attribute__((address_space(3))) void*)l, 16, 0, 0);
}

__device__ __forceinline__ ushort f2bf(float x) {
    __hip_bfloat16 h = __float2bfloat16(x);
    return *reinterpret_cast<ushort*>(&h);
}

__device__ __forceinline__ uint pack2(float a, float b) {
    return (uint)f2bf(a) | ((uint)f2bf(b) << 16);
}

// Stage one 256x32 bf16 slab (16 KB) = 2 x global_load_lds_dwordx4 / thread.
// LDS linear chunk (row, cs) <- global chunk (row, cs ^ ((row>>1)&3)).
__device__ __forceinline__ void stage_tile(const ushort* __restrict__ g,
                                           ushort* l, int grow0, int kt,
                                           int rmax, int tid)
{
#pragma unroll
    for (int j = 0; j < 2; ++j) {
        const int ch = j * 512 + tid;          // 0..1023
        const int row = ch >> 2;               // 0..255
        const int cs = ch & 3;                 // slot chunk in 64 B row
        const int gc = cs ^ ((row >> 1) & 3);  // global chunk
        const int gr = min(grow0 + row, rmax); // clamp partial tile
        load_lds16(g + (size_t)gr * D + kt * BK + gc * 8, l + (size_t)ch * 8);
    }
}

// ---- bf16 MFMA GEMM: C[M,NC] = A[M,D] @ BT[NP,D]^T (cols >= NC dropped) ----
__global__ __launch_bounds__(512, 2) void gemm_bf16_mfma(
    const ushort* __restrict__ A, const ushort* __restrict__ BT,
    ushort* __restrict__ C, int M, int nwg)
{
    __shared__ alignas(16) ushort As[4][BM * BK];   // 64 KB ring
    __shared__ alignas(16) ushort Bs[4][BN * BK];   // 64 KB ring

    // bijective XCD-aware remap (m204): each XCD gets contiguous wg range
    const int o = blockIdx.x;
    const int xcd = o & 7, lid = o >> 3;
    const int q = nwg >> 3, r = nwg & 7;
    const int wg = (xcd < r ? xcd * (q + 1) : r * (q + 1) + (xcd - r) * q) + lid;
    const int bnt = wg % NTN, bmt = wg / NTN;
    const int bm = bmt * BM, bn = bnt * BN;

    const int tid = threadIdx.x;
    const int wave = tid >> 6, lane = tid & 63;
    const int wr = wave >> 2, wc = wave & 3;   // 2M x 4N wave grid
    const int l15 = lane & 15, k8 = lane >> 4;

    floatx4 acc[8][4] = {};

    // prologue: stage K-tiles 0,1,2 (12 loads); wait until kt0 landed
    stage_tile(A, As[0], bm, 0, M - 1, tid);
    stage_tile(BT, Bs[0], bn, 0, NP - 1, tid);
    stage_tile(A, As[1], bm, 1, M - 1, tid);
    stage_tile(BT, Bs[1], bn, 1, NP - 1, tid);
    stage_tile(A, As[2], bm, 2, M - 1, tid);
    stage_tile(BT, Bs[2], bn, 2, NP - 1, tid);
    WAIT_VM8();
    BAR();

    short8 bf[4];
    for (int j = 0; j < NKT; ++j) {
        const ushort* Ab = As[j & 3];
        const ushort* Bb = Bs[j & 3];
        const int js = j + 3;
        const int sb = js & 3;

        // ---- phase 1: m-half 0; read A+B frags; stage A(j+3) ----
        short8 af[4];
#pragma unroll
        for (int mi = 0; mi < 4; ++mi) {
            const int m = wr * 128 + mi * 16 + l15;
            af[mi] = *(const short8*)(Ab + m * BK + ((k8 ^ ((m >> 1) & 3)) << 3));
        }
#pragma unroll
        for (int ni = 0; ni < 4; ++ni) {
            const int n = wc * 64 + ni * 16 + l15;
            bf[ni] = *(const short8*)(Bb + n * BK + ((k8 ^ ((n >> 1) & 3)) << 3));
        }
        if (js < NKT) stage_tile(A, As[sb], bm, js, M - 1, tid);
        BAR();
        WAIT_LGKM0();
        __builtin_amdgcn_sched_barrier(0);
        __builtin_amdgcn_s_setprio(1);
#pragma unroll
        for (int mi = 0; mi < 4; ++mi)
#pragma unroll
            for (int ni = 0; ni < 4; ++ni)
                acc[mi][ni] = __builtin_amdgcn_mfma_f32_16x16x32_bf16(
                    af[mi], bf[ni], acc[mi][ni], 0, 0, 0);
        __builtin_amdgcn_s_setprio(0);
        BAR();

        // ---- phase 2: m-half 1; reuse B frags; stage B(j+3) ----
#pragma unroll
        for (int mi = 0; mi < 4; ++mi) {
            const int m = wr * 128 + 64 + mi * 16 + l15;
            af[mi] = *(const short8*)(Ab + m * BK + ((k8 ^ ((m >> 1) & 3)) << 3));
        }
        if (js < NKT) stage_tile(BT, Bs[sb], bn, js, NP - 1, tid);
        BAR();
        WAIT_LGKM0();
        __builtin_amdgcn_sched_barrier(0);
        __builtin_amdgcn_s_setprio(1);
#pragma unroll
        for (int mi = 0; mi < 4; ++mi)
#pragma unroll
            for (int ni = 0; ni < 4; ++ni)
                acc[4 + mi][ni] = __builtin_amdgcn_mfma_f32_16x16x32_bf16(
                    af[mi], bf[ni], acc[4 + mi][ni], 0, 0, 0);
        __builtin_amdgcn_s_setprio(0);
        // counted drain: guarantee K-tile j+1 landed; leave j+2, j+3 in flight
        if (j < NKT - 3)       { WAIT_VM8(); }
        else if (j == NKT - 3) { WAIT_VM4(); }
        else if (j == NKT - 2) { WAIT_VM0(); }
        BAR();
    }

    // epilogue: C/D layout col=lane&15, row=(lane>>4)*4+reg
    if (bm + BM <= M && bn + BN <= NC) {
#pragma unroll
        for (int a = 0; a < 8; ++a) {
            const int rbase = bm + wr * 128 + (a >> 2) * 64 + (a & 3) * 16 + k8 * 4;
#pragma unroll
            for (int reg = 0; reg < 4; ++reg) {
                const int row = rbase + reg;
#pragma unroll
                for (int ni = 0; ni < 4; ++ni) {
                    const int col = bn + wc * 64 + ni * 16 + l15;
                    C[(size_t)row * NC + col] = f2bf(acc[a][ni][reg]);
                }
            }
        }
    } else {
#pragma unroll
        for (int a = 0; a < 8; ++a) {
            const int rbase = bm + wr * 128 + (a >> 2) * 64 + (a & 3) * 16 + k8 * 4;
#pragma unroll
            for (int reg = 0; reg < 4; ++reg) {
                const int row = rbase + reg;
                if (row < M) {
#pragma unroll
                    for (int ni = 0; ni < 4; ++ni) {
                        const int col = bn + wc * 64 + ni * 16 + l15;
                        if (col < NC)
                            C[(size_t)row * NC + col] = f2bf(acc[a][ni][reg]);
                    }
                }
            }
        }
    }
}

// ---- preprocessing: CSR by (rel, dst) ----

__global__ __launch_bounds__(256) void count_edges(
    const int* __restrict__ dst, const int* __restrict__ et,
    int* __restrict__ cntI, int E, int M)
{
    const int e = blockIdx.x * blockDim.x + threadIdx.x;
    if (e < E) atomicAdd(&cntI[(size_t)et[e] * M + dst[e]], 1);
}

__global__ __launch_bounds__(256) void finalize_cnt(
    const int* __restrict__ cntI, float* __restrict__ invc, int n)
{
    const int i = blockIdx.x * blockDim.x + threadIdx.x;
    if (i < n) invc[i] = 1.0f / (float)max(cntI[i], 1);
}

// ---- 3-kernel hierarchical exclusive scan (n ~ 100k) ----
__global__ __launch_bounds__(1024) void scan_local(
    const int* __restrict__ hist, int* __restrict__ offs,
    int* __restrict__ bsums, int n)
{
    __shared__ int tmp[1024];
    const int tid = threadIdx.x;
    const int i = blockIdx.x * 1024 + tid;
    const int v = (i < n) ? hist[i] : 0;
    tmp[tid] = v;
    __syncthreads();
#pragma unroll
    for (int off = 1; off < 1024; off <<= 1) {
        const int add = (tid >= off) ? tmp[tid - off] : 0;
        __syncthreads();
        tmp[tid] += add;
        __syncthreads();
    }
    if (i < n) offs[i] = tmp[tid] - v;
    if (tid == 1023) bsums[blockIdx.x] = tmp[1023];
}

__global__ __launch_bounds__(1024) void scan_bsums(
    int* __restrict__ bsums, int* __restrict__ total_out, int nb)
{
    __shared__ int tmp[1024];
    const int tid = threadIdx.x;
    const int v = (tid < nb) ? bsums[tid] : 0;
    tmp[tid] = v;
    __syncthreads();
#pragma unroll
    for (int off = 1; off < 1024; off <<= 1) {
        const int add = (tid >= off) ? tmp[tid - off] : 0;
        __syncthreads();
        tmp[tid] += add;
        __syncthreads();
    }
    if (tid < nb) bsums[tid] = tmp[tid] - v;
    if (tid == 1023) *total_out = tmp[1023];
}

__global__ __launch_bounds__(1024) void scan_add(
    int* __restrict__ offs, const int* __restrict__ bsums, int n)
{
    const int i = blockIdx.x * 1024 + threadIdx.x;
    if (i < n) offs[i] += bsums[blockIdx.x];
}

__global__ __launch_bounds__(256) void fill_sorted(
    const int* __restrict__ src, const int* __restrict__ dst,
    const int* __restrict__ et, const int* __restrict__ offs,
    int* __restrict__ cursor, int* __restrict__ sorted, int E, int M)
{
    const int e = blockIdx.x * blockDim.x + threadIdx.x;
    if (e < E) {
        const int key = et[e] * M + dst[e];
        const int pos = offs[key] + atomicAdd(&cursor[key], 1);
        sorted[pos] = src[e];
    }
}

// ---- weights -> concatenated B^T bf16 [NP, D] per layer (rows >= NC pad) ----
__global__ __launch_bounds__(256) void build_bt(
    const float* __restrict__ root1, const float* __restrict__ W1,
    const float* __restrict__ root2, const float* __restrict__ W2,
    const float* __restrict__ root3, const float* __restrict__ W3,
    ushort* __restrict__ BT)
{
    __shared__ float tile[32][33];
    const int l = blockIdx.z;
    const float* root = (l == 0) ? root1 : (l == 1) ? root2 : root3;
    const float* W    = (l == 0) ? W1    : (l == 1) ? W2    : W3;
    const int kt = blockIdx.x * 32;
    const int nt = blockIdx.y * 32;
    const int tx = threadIdx.x & 31;
    const int ty = threadIdx.x >> 5;
    const float* srcm;
    int noff;
    if (nt < D)          { srcm = root;      noff = 0; }
    else if (nt < 2 * D) { srcm = W;         noff = D; }
    else                 { srcm = W + D * D; noff = 2 * D; }
    const int n = nt - noff + tx;
#pragma unroll
    for (int i = 0; i < 4; ++i) {
        const int k = kt + ty + i * 8;
        tile[ty + i * 8][tx] = srcm[(size_t)k * D + n];
    }
    __syncthreads();
    ushort* dst = BT + (size_t)l * NP * D;
#pragma unroll
    for (int i = 0; i < 4; ++i) {
        const int nn = nt + ty + i * 8;
        const int kk = kt + tx;
        dst[(size_t)nn * D + kk] = f2bf(tile[tx][ty + i * 8]);
    }
}

__global__ __launch_bounds__(256) void cast_f32_to_bf16(
    const float* __restrict__ x, ushort* __restrict__ y, int n4)
{
    const int i = blockIdx.x * blockDim.x + threadIdx.x;
    if (i < n4) {
        const float4 v = ((const float4*)x)[i];
        uint2 o;
        o.x = pack2(v.x, v.y);
        o.y = pack2(v.z, v.w);
        ((uint2*)y)[i] = o;
    }
}

// ---- fused aggregation: one wave per node, both relations + root + bias ----
__global__ __launch_bounds__(256) void aggregate_all(
    const ushort* __restrict__ TC, const int* __restrict__ sorted,
    const int* __restrict__ offs, const float* __restrict__ invc,
    const float* __restrict__ bias, ushort* __restrict__ outb,
    float* __restrict__ outf, int M, int relu)
{
    const int wave = threadIdx.x >> 6;
    const int lane = threadIdx.x & 63;
    const int d = blockIdx.x * 4 + wave;
    if (d >= M) return;

    float v[6];
    {
        const uint* rp = (const uint*)(TC + (size_t)d * NC);
#pragma unroll
        for (int p = 0; p < 3; ++p) {
            const uint b = rp[lane + 64 * p];
            const float2 bb = *(const float2*)(bias + (lane + 64 * p) * 2);
            v[2 * p]     = __uint_as_float(b << 16) + bb.x;
            v[2 * p + 1] = __uint_as_float(b & 0xffff0000u) + bb.y;
        }
    }
#pragma unroll
    for (int r = 0; r < 2; ++r) {
        const int key = r * M + d;
        const int beg = offs[key], end = offs[key + 1];
        float g[6] = {0.f, 0.f, 0.f, 0.f, 0.f, 0.f};
        for (int i = beg; i < end; ++i) {
            const int s = sorted[i];
            const uint* tp = (const uint*)(TC + (size_t)s * NC + D + r * D);
#pragma unroll
            for (int p = 0; p < 3; ++p) {
                const uint b = tp[lane + 64 * p];
                g[2 * p]     += __uint_as_float(b << 16);
                g[2 * p + 1] += __uint_as_float(b & 0xffff0000u);
            }
        }
        const float ic = invc[key];
#pragma unroll
        for (int j = 0; j < 6; ++j) v[j] += ic * g[j];
    }
    if (relu) {
#pragma unroll
        for (int j = 0; j < 6; ++j) v[j] = fmaxf(v[j], 0.f);
    }
    if (outb) {
        uint* op = (uint*)(outb + (size_t)d * D);
#pragma unroll
        for (int p = 0; p < 3; ++p) op[lane + 64 * p] = pack2(v[2 * p], v[2 * p + 1]);
    } else {
        float2* op = (float2*)(outf + (size_t)d * D);
#pragma unroll
        for (int p = 0; p < 3; ++p)
            op[lane + 64 * p] = make_float2(v[2 * p], v[2 * p + 1]);
    }
}

extern "C" void kernel_launch(void* const* d_in, const int* in_sizes, int n_in,
                              void* d_out, int out_size, void* d_ws, size_t ws_size,
                              hipStream_t stream)
{
    const float* emb   = (const float*)d_in[0];
    const int*   eidx  = (const int*)d_in[1];
    const int*   et    = (const int*)d_in[2];
    const float* W1    = (const float*)d_in[3];
    const float* root1 = (const float*)d_in[4];
    const float* bias1 = (const float*)d_in[5];
    const float* W2    = (const float*)d_in[6];
    const float* root2 = (const float*)d_in[7];
    const float* bias2 = (const float*)d_in[8];
    const float* W3    = (const float*)d_in[9];
    const float* root3 = (const float*)d_in[10];
    const float* bias3 = (const float*)d_in[11];

    float* out = (float*)d_out;
    const int M = in_sizes[0] / D;   // 50000
    const int E = in_sizes[1] / 2;   // 200000
    const int* src  = eidx;
    const int* dstv = eidx + E;

    const int n = 2 * M;
    const int nb = (n + 1023) / 1024;

    // Workspace: TC[M*NC]bf16 | Xb[M*D]bf16 | BT[3*NP*D]bf16 |
    //            invcnt[2M]f32 | cntI[2M]i32 | offs[2M+1]i32 | sorted[E]i32 |
    //            bsums[nb]i32
    char* w = (char*)d_ws;
    ushort* TC = (ushort*)w;          w += (size_t)M * NC * 2;
    ushort* Xb = (ushort*)w;          w += (size_t)M * D * 2;
    ushort* BT = (ushort*)w;          w += (size_t)3 * NP * D * 2;
    float* invcnt = (float*)w;        w += (size_t)n * 4;
    int* cntI = (int*)w;              w += (size_t)n * 4;
    int* offs = (int*)w;              w += ((size_t)n + 1) * 4;
    int* sorted = (int*)w;            w += (size_t)E * 4;
    int* bsums = (int*)w;

    // --- preprocessing ---
    hipMemsetAsync(cntI, 0, (size_t)n * sizeof(int), stream);
    count_edges<<<(E + 255) / 256, 256, 0, stream>>>(dstv, et, cntI, E, M);
    finalize_cnt<<<(n + 255) / 256, 256, 0, stream>>>(cntI, invcnt, n);
    scan_local<<<nb, 1024, 0, stream>>>(cntI, offs, bsums, n);
    scan_bsums<<<1, 1024, 0, stream>>>(bsums, offs + n, nb);
    scan_add<<<nb, 1024, 0, stream>>>(offs, bsums, n);
    hipMemsetAsync(cntI, 0, (size_t)n * sizeof(int), stream);
    fill_sorted<<<(E + 255) / 256, 256, 0, stream>>>(src, dstv, et, offs, cntI, sorted, E, M);

    build_bt<<<dim3(D / 32, NC / 32, 3), 256, 0, stream>>>(root1, W1, root2, W2, root3, W3, BT);
    cast_f32_to_bf16<<<(M * D / 4 + 255) / 256, 256, 0, stream>>>(emb, Xb, M * D / 4);

    // GEMM grid: Mtiles x 5 padded N-tiles, bijective XCD swizzle in-kernel
    const int Mtiles = (M + BM - 1) / BM;
    const int nwg = Mtiles * NTN;
    const float* biases[3] = {bias1, bias2, bias3};
    for (int l = 0; l < 3; ++l) {
        gemm_bf16_mfma<<<nwg, 512, 0, stream>>>(Xb, BT + (size_t)l * NP * D, TC, M, nwg);
        const bool last = (l == 2);
        aggregate_all<<<(M + 3) / 4, 256, 0, stream>>>(
            TC, sorted, offs, invcnt, biases[l],
            last ? nullptr : Xb, last ? out : nullptr, M, last ? 0 : 1);
    }
}